// Round 2
// baseline (503.158 us; speedup 1.0000x reference)
//
#include <hip/hip_runtime.h>
#include <hip/hip_bf16.h>

#define NBATCH 32
#define Ls 1024
#define Ds 1024
#define Hs 1024

typedef float f32x4 __attribute__((ext_vector_type(4)));
typedef __bf16 v8bf __attribute__((ext_vector_type(8)));
typedef __hip_bfloat16 bf16;

struct bf4 { bf16 a, b, c, d; };   // 8 bytes

// ---------------- normalize q,k rows -> bf16 ----------------
__global__ __launch_bounds__(256) void k_norm(const float* __restrict__ q,
                                              const float* __restrict__ k,
                                              bf16* __restrict__ qn,
                                              bf16* __restrict__ kn) {
  const size_t row = blockIdx.x;
  const int t = threadIdx.x;
  const float4 qv = reinterpret_cast<const float4*>(q + row * Ds)[t];
  const float4 kv = reinterpret_cast<const float4*>(k + row * Ds)[t];
  float sq = qv.x*qv.x + qv.y*qv.y + qv.z*qv.z + qv.w*qv.w;
  float sk = kv.x*kv.x + kv.y*kv.y + kv.z*kv.z + kv.w*kv.w;
  #pragma unroll
  for (int o = 32; o > 0; o >>= 1) { sq += __shfl_down(sq, o); sk += __shfl_down(sk, o); }
  __shared__ float rq[4], rk[4];
  if ((t & 63) == 0) { rq[t >> 6] = sq; rk[t >> 6] = sk; }
  __syncthreads();
  const float invq = 1.0f / sqrtf(rq[0] + rq[1] + rq[2] + rq[3]);
  const float invk = 1.0f / sqrtf(rk[0] + rk[1] + rk[2] + rk[3]);
  bf4 oq = { __float2bfloat16(qv.x * invq), __float2bfloat16(qv.y * invq),
             __float2bfloat16(qv.z * invq), __float2bfloat16(qv.w * invq) };
  bf4 ok = { __float2bfloat16(kv.x * invk), __float2bfloat16(kv.y * invk),
             __float2bfloat16(kv.z * invk), __float2bfloat16(kv.w * invk) };
  reinterpret_cast<bf4*>(qn + row * Ds)[t] = oq;
  reinterpret_cast<bf4*>(kn + row * Ds)[t] = ok;
}

// ---------------- keys -> keysT bf16 (per batch) ----------------
__global__ __launch_bounds__(256) void k_transpose(const float* __restrict__ k,
                                                   bf16* __restrict__ kT) {
  __shared__ float tile[64][65];
  const int b = blockIdx.z;
  const int d0 = blockIdx.x * 64, j0 = blockIdx.y * 64;
  const int tx = threadIdx.x, ty = threadIdx.y;
  const float* src = k + (size_t)b * Ls * Ds;
  #pragma unroll
  for (int r = 0; r < 16; ++r)
    tile[ty + r * 4][tx] = src[(size_t)(j0 + ty + r * 4) * Ds + d0 + tx];
  __syncthreads();
  bf16* dst = kT + (size_t)b * Ds * Ls;
  #pragma unroll
  for (int r = 0; r < 16; ++r)
    dst[(size_t)(d0 + ty + r * 4) * Ls + j0 + tx] = __float2bfloat16(tile[tx][ty + r * 4]);
}

// ---------------- W -> W2 = [wh | wh | wl] bf16 ----------------
__global__ __launch_bounds__(256) void k_w2(const float* __restrict__ W,
                                            bf16* __restrict__ W2) {
  const size_t idx = (size_t)blockIdx.x * 256 + threadIdx.x;   // over H*D
  const size_t h = idx >> 10, d = idx & 1023;
  const float w = W[idx];
  const bf16 wh = __float2bfloat16(w);
  const bf16 wl = __float2bfloat16(w - __bfloat162float(wh));
  bf16* row = W2 + h * 3072;
  row[d] = wh; row[1024 + d] = wh; row[2048 + d] = wl;
}

// ---------------- generic NT bf16 GEMM: C[i][j] = sum_k A[i,k]*B[j,k] ----------------
// 128x128 tile, BK=32, 4 waves (2x2), 16x16x32 MFMA, global_load_lds staging.
template<int EPI>   // 0 = plain fp32 store, 1 = bias + relu
__global__ __launch_bounds__(256) void k_gemm_nt(
    const bf16* __restrict__ A, const bf16* __restrict__ B,
    float* __restrict__ C, const float* __restrict__ bias,
    int lda, int ldb, int ldc, int K, int nb,
    size_t sA, size_t sB, size_t zA, size_t zB, size_t zC)
{
  __shared__ bf16 As[128 * 32];
  __shared__ bf16 Bs[128 * 32];
  const int tid = threadIdx.x;
  const int lane = tid & 63;
  const int wc = (tid >> 6) & 1;      // wave col
  const int wr = (tid >> 7) & 1;      // wave row
  const size_t m0 = (size_t)blockIdx.y * 128;
  const size_t n0 = (size_t)blockIdx.x * 128;
  const bf16* Az = A + (size_t)blockIdx.z * zA;
  const bf16* Bz = B + (size_t)blockIdx.z * zB;
  float* Cz = C + (size_t)blockIdx.z * zC;
  f32x4 acc[4][4] = {};

  // staging: LDS byte beta = tid*16 (+4096 for chunk 1); row = beta/64, kk = (beta%64)/2
  const int beta0 = tid * 16;
  const int row0 = beta0 >> 6;
  const int kk0 = (beta0 & 63) >> 1;
  const int hk = (lane >> 4) * 16;    // byte offset of this lane's 8-elem k-slice

  for (int b = 0; b < nb; ++b) {
    const bf16* Abp = Az + (size_t)b * sA;
    const bf16* Bbp = Bz + (size_t)b * sB;
    for (int k0 = 0; k0 < K; k0 += 32) {
      __syncthreads();
      __builtin_amdgcn_global_load_lds(
          (__attribute__((address_space(1))) void*)(Abp + (m0 + row0) * lda + (k0 + kk0)),
          (__attribute__((address_space(3))) void*)(&As[beta0 / 2]), 16, 0, 0);
      __builtin_amdgcn_global_load_lds(
          (__attribute__((address_space(1))) void*)(Abp + (m0 + row0 + 64) * lda + (k0 + kk0)),
          (__attribute__((address_space(3))) void*)(&As[beta0 / 2 + 2048]), 16, 0, 0);
      __builtin_amdgcn_global_load_lds(
          (__attribute__((address_space(1))) void*)(Bbp + (n0 + row0) * ldb + (k0 + kk0)),
          (__attribute__((address_space(3))) void*)(&Bs[beta0 / 2]), 16, 0, 0);
      __builtin_amdgcn_global_load_lds(
          (__attribute__((address_space(1))) void*)(Bbp + (n0 + row0 + 64) * ldb + (k0 + kk0)),
          (__attribute__((address_space(3))) void*)(&Bs[beta0 / 2 + 2048]), 16, 0, 0);
      __syncthreads();

      v8bf af[4], bg[4];
      #pragma unroll
      for (int m = 0; m < 4; ++m) {
        const int rA = wr * 64 + m * 16 + (lane & 15);
        af[m] = *reinterpret_cast<const v8bf*>(reinterpret_cast<const char*>(As) + rA * 64 + hk);
        const int rB = wc * 64 + m * 16 + (lane & 15);
        bg[m] = *reinterpret_cast<const v8bf*>(reinterpret_cast<const char*>(Bs) + rB * 64 + hk);
      }
      #pragma unroll
      for (int m = 0; m < 4; ++m)
        #pragma unroll
        for (int n = 0; n < 4; ++n)
          acc[m][n] = __builtin_amdgcn_mfma_f32_16x16x32_bf16(af[m], bg[n], acc[m][n], 0, 0, 0);
    }
  }

  // epilogue: C/D layout col=lane&15, row=(lane>>4)*4+reg
  #pragma unroll
  for (int m = 0; m < 4; ++m) {
    const size_t ri = m0 + wr * 64 + m * 16 + ((lane >> 4) * 4);
    #pragma unroll
    for (int n = 0; n < 4; ++n) {
      const size_t cj = n0 + wc * 64 + n * 16 + (lane & 15);
      float bv = 0.0f;
      if (EPI == 1) bv = bias[cj];
      #pragma unroll
      for (int r = 0; r < 4; ++r) {
        float v = acc[m][n][r];
        if (EPI == 1) v = fmaxf(v + bv, 0.0f);
        Cz[(ri + r) * ldc + cj] = v;
      }
    }
  }
}

// ---------------- softmax over rows, in place, + bf16 copy ----------------
__global__ __launch_bounds__(256) void k_softmax(float* __restrict__ sc,
                                                 bf16* __restrict__ abf) {
  const size_t row = blockIdx.x;
  const int t = threadIdx.x;
  float* s = sc + row * Ls;
  float4 v = reinterpret_cast<float4*>(s)[t];
  float mx = fmaxf(fmaxf(v.x, v.y), fmaxf(v.z, v.w));
  #pragma unroll
  for (int o = 32; o > 0; o >>= 1) mx = fmaxf(mx, __shfl_down(mx, o));
  __shared__ float rm[4], rs[4];
  if ((t & 63) == 0) rm[t >> 6] = mx;
  __syncthreads();
  const float M = fmaxf(fmaxf(rm[0], rm[1]), fmaxf(rm[2], rm[3]));
  float4 e;
  e.x = __expf(v.x - M); e.y = __expf(v.y - M);
  e.z = __expf(v.z - M); e.w = __expf(v.w - M);
  float ss = e.x + e.y + e.z + e.w;
  #pragma unroll
  for (int o = 32; o > 0; o >>= 1) ss += __shfl_down(ss, o);
  if ((t & 63) == 0) rs[t >> 6] = ss;
  __syncthreads();
  const float inv = 1.0f / (rs[0] + rs[1] + rs[2] + rs[3]);
  e.x *= inv; e.y *= inv; e.z *= inv; e.w *= inv;
  reinterpret_cast<float4*>(s)[t] = e;
  bf4 o4 = { __float2bfloat16(e.x), __float2bfloat16(e.y),
             __float2bfloat16(e.z), __float2bfloat16(e.w) };
  reinterpret_cast<bf4*>(abf + row * Ls)[t] = o4;
}

// ---------------- reduce split-K partials -> A2 = [ah | al | ah] ----------------
__global__ __launch_bounds__(256) void k_reduce(const float* __restrict__ part,
                                                bf16* __restrict__ A2) {
  const size_t idx = (size_t)blockIdx.x * 256 + threadIdx.x;   // over L*D
  float s = 0.0f;
  #pragma unroll
  for (int g = 0; g < 16; ++g) s += part[(size_t)g * (Ls * Ds) + idx];
  const size_t i = idx >> 10, d = idx & 1023;
  const bf16 ah = __float2bfloat16(s);
  const bf16 al = __float2bfloat16(s - __bfloat162float(ah));
  bf16* row = A2 + i * 3072;
  row[d] = ah; row[1024 + d] = al; row[2048 + d] = ah;
}

extern "C" void kernel_launch(void* const* d_in, const int* in_sizes, int n_in,
                              void* d_out, int out_size, void* d_ws, size_t ws_size,
                              hipStream_t stream) {
  const float* q = (const float*)d_in[0];
  const float* k = (const float*)d_in[1];
  const float* W = (const float*)d_in[2];
  const float* bias = (const float*)d_in[3];
  float* xout = (float*)d_out;                        // [1024][1024]
  float* attn = (float*)d_out + (size_t)Ls * Hs;      // [32][1024][1024] (scores staged here)

  char* w = (char*)d_ws;
  bf16* qn = (bf16*)w;                                // 64 MB; reused as attn bf16
  bf16* kn = (bf16*)(w + ((size_t)64 << 20));         // 64 MB; reused as partials
  bf16* kT = (bf16*)(w + ((size_t)128 << 20));        // 64 MB
  bf16* W2 = (bf16*)(w + ((size_t)192 << 20));        // 6 MB
  bf16* A2 = (bf16*)(w + ((size_t)199 << 20));        // 6 MB
  float* part = (float*)kn;                           // 64 MB (16 groups x 4 MB)
  bf16* abf = qn;

  k_norm<<<NBATCH * Ls, 256, 0, stream>>>(q, k, qn, kn);
  k_transpose<<<dim3(16, 16, NBATCH), dim3(64, 4), 0, stream>>>(k, kT);
  k_w2<<<(Hs * Ds) / 256, 256, 0, stream>>>(W, W2);

  // scores[b][i][j] = kn_b . qn_b^T  -> fp32 into d_out attn region
  k_gemm_nt<0><<<dim3(8, 8, NBATCH), 256, 0, stream>>>(kn, qn, attn, nullptr,
      Ds, Ds, Ls, Ds, 1, 0, 0,
      (size_t)Ls * Ds, (size_t)Ls * Ds, (size_t)Ls * Ls);

  k_softmax<<<NBATCH * Ls, 256, 0, stream>>>(attn, abf);

  // out partials: 16 z-groups x 2 batches each; C_z[i][d] += attn_b[i,:] . kT_b[d,:]
  k_gemm_nt<0><<<dim3(8, 8, 16), 256, 0, stream>>>(abf, kT, part, nullptr,
      Ls, Ls, Ds, Ls, 2, (size_t)Ls * Ls, (size_t)Ls * Ds,
      (size_t)2 * Ls * Ls, (size_t)2 * Ls * Ds, (size_t)Ls * Ds);

  k_reduce<<<(Ls * Ds) / 256, 256, 0, stream>>>(part, A2);

  // x = relu(A2 . W2^T + b)  (hi/lo split, K=3072)
  k_gemm_nt<1><<<dim3(8, 8, 1), 256, 0, stream>>>(A2, W2, xout, bias,
      3072, 3072, Hs, 3072, 1, 0, 0, 0, 0, 0);
}

// Round 3
// 457.920 us; speedup vs baseline: 1.0988x; 1.0988x over previous
//
#include <hip/hip_runtime.h>
#include <hip/hip_bf16.h>

#define NBATCH 32
#define Ls 1024
#define Ds 1024
#define Hs 1024

typedef float f32x4 __attribute__((ext_vector_type(4)));
typedef __bf16 v8bf __attribute__((ext_vector_type(8)));
typedef __hip_bfloat16 bf16;

struct bf4 { bf16 a, b, c, d; };   // 8 bytes

// ---------------- normalize q,k rows -> bf16 ----------------
__global__ __launch_bounds__(256) void k_norm(const float* __restrict__ q,
                                              const float* __restrict__ k,
                                              bf16* __restrict__ qn,
                                              bf16* __restrict__ kn) {
  const size_t row = blockIdx.x;
  const int t = threadIdx.x;
  const float4 qv = reinterpret_cast<const float4*>(q + row * Ds)[t];
  const float4 kv = reinterpret_cast<const float4*>(k + row * Ds)[t];
  float sq = qv.x*qv.x + qv.y*qv.y + qv.z*qv.z + qv.w*qv.w;
  float sk = kv.x*kv.x + kv.y*kv.y + kv.z*kv.z + kv.w*kv.w;
  #pragma unroll
  for (int o = 32; o > 0; o >>= 1) { sq += __shfl_down(sq, o); sk += __shfl_down(sk, o); }
  __shared__ float rq[4], rk[4];
  if ((t & 63) == 0) { rq[t >> 6] = sq; rk[t >> 6] = sk; }
  __syncthreads();
  const float invq = 1.0f / sqrtf(rq[0] + rq[1] + rq[2] + rq[3]);
  const float invk = 1.0f / sqrtf(rk[0] + rk[1] + rk[2] + rk[3]);
  bf4 oq = { __float2bfloat16(qv.x * invq), __float2bfloat16(qv.y * invq),
             __float2bfloat16(qv.z * invq), __float2bfloat16(qv.w * invq) };
  bf4 ok = { __float2bfloat16(kv.x * invk), __float2bfloat16(kv.y * invk),
             __float2bfloat16(kv.z * invk), __float2bfloat16(kv.w * invk) };
  reinterpret_cast<bf4*>(qn + row * Ds)[t] = oq;
  reinterpret_cast<bf4*>(kn + row * Ds)[t] = ok;
}

// ---------------- keys -> keysT bf16 (per batch) ----------------
__global__ __launch_bounds__(256) void k_transpose(const float* __restrict__ k,
                                                   bf16* __restrict__ kT) {
  __shared__ float tile[64][65];
  const int b = blockIdx.z;
  const int d0 = blockIdx.x * 64, j0 = blockIdx.y * 64;
  const int tx = threadIdx.x, ty = threadIdx.y;
  const float* src = k + (size_t)b * Ls * Ds;
  #pragma unroll
  for (int r = 0; r < 16; ++r)
    tile[ty + r * 4][tx] = src[(size_t)(j0 + ty + r * 4) * Ds + d0 + tx];
  __syncthreads();
  bf16* dst = kT + (size_t)b * Ds * Ls;
  #pragma unroll
  for (int r = 0; r < 16; ++r)
    dst[(size_t)(d0 + ty + r * 4) * Ls + j0 + tx] = __float2bfloat16(tile[tx][ty + r * 4]);
}

// ---------------- W -> W2 = [wh | wh | wl] bf16 ----------------
__global__ __launch_bounds__(256) void k_w2(const float* __restrict__ W,
                                            bf16* __restrict__ W2) {
  const size_t idx = (size_t)blockIdx.x * 256 + threadIdx.x;   // over H*D
  const size_t h = idx >> 10, d = idx & 1023;
  const float w = W[idx];
  const bf16 wh = __float2bfloat16(w);
  const bf16 wl = __float2bfloat16(w - __bfloat162float(wh));
  bf16* row = W2 + h * 3072;
  row[d] = wh; row[1024 + d] = wh; row[2048 + d] = wl;
}

// ---------------- generic NT bf16 GEMM: C[i][j] = sum_k A[i,k]*B[j,k] ----------------
// 128x128 tile, BK=32, 4 waves (2x2), 16x16x32 MFMA, global_load_lds staging.
// LDS k-slice swizzle (rule 21): slot (row,s) holds global k-slice s^((row>>1)&3);
// store side pre-permutes the per-lane GLOBAL address, read side XORs the ds_read addr.
template<int EPI>   // 0 = plain fp32 store, 1 = bias + relu
__global__ __launch_bounds__(256) void k_gemm_nt(
    const bf16* __restrict__ A, const bf16* __restrict__ B,
    float* __restrict__ C, const float* __restrict__ bias,
    int lda, int ldb, int ldc, int K, int nb,
    size_t sA, size_t sB, size_t zA, size_t zB, size_t zC)
{
  __shared__ bf16 As[128 * 32];
  __shared__ bf16 Bs[128 * 32];
  const int tid = threadIdx.x;
  const int lane = tid & 63;
  const int wc = (tid >> 6) & 1;      // wave col
  const int wr = (tid >> 7) & 1;      // wave row
  const size_t m0 = (size_t)blockIdx.y * 128;
  const size_t n0 = (size_t)blockIdx.x * 128;
  const bf16* Az = A + (size_t)blockIdx.z * zA;
  const bf16* Bz = B + (size_t)blockIdx.z * zB;
  float* Cz = C + (size_t)blockIdx.z * zC;
  f32x4 acc[4][4] = {};

  // staging: thread tid -> LDS byte tid*16 (linear dest), row = tid>>2, slot s = tid&3.
  // global k-slice to fetch = s ^ ((row>>1)&3)   (same for row and row+64)
  const int beta0 = tid * 16;
  const int row0 = tid >> 2;
  const int kk0 = ((tid & 3) ^ ((row0 >> 1) & 3)) * 8;   // element offset in row
  // read-side swizzle: byte = rA*64 + ((lane>>4) ^ ((lane>>1)&3))*16
  const int sw = (((lane >> 4) ^ ((lane >> 1) & 3)) << 4);
  const int rsel = lane & 15;

  for (int b = 0; b < nb; ++b) {
    const bf16* Abp = Az + (size_t)b * sA;
    const bf16* Bbp = Bz + (size_t)b * sB;
    for (int k0 = 0; k0 < K; k0 += 32) {
      __syncthreads();
      __builtin_amdgcn_global_load_lds(
          (__attribute__((address_space(1))) void*)(Abp + (m0 + row0) * lda + (k0 + kk0)),
          (__attribute__((address_space(3))) void*)(&As[beta0 / 2]), 16, 0, 0);
      __builtin_amdgcn_global_load_lds(
          (__attribute__((address_space(1))) void*)(Abp + (m0 + row0 + 64) * lda + (k0 + kk0)),
          (__attribute__((address_space(3))) void*)(&As[beta0 / 2 + 2048]), 16, 0, 0);
      __builtin_amdgcn_global_load_lds(
          (__attribute__((address_space(1))) void*)(Bbp + (n0 + row0) * ldb + (k0 + kk0)),
          (__attribute__((address_space(3))) void*)(&Bs[beta0 / 2]), 16, 0, 0);
      __builtin_amdgcn_global_load_lds(
          (__attribute__((address_space(1))) void*)(Bbp + (n0 + row0 + 64) * ldb + (k0 + kk0)),
          (__attribute__((address_space(3))) void*)(&Bs[beta0 / 2 + 2048]), 16, 0, 0);
      __syncthreads();

      v8bf af[4], bg[4];
      #pragma unroll
      for (int m = 0; m < 4; ++m) {
        const int rA = wr * 64 + m * 16 + rsel;
        af[m] = *reinterpret_cast<const v8bf*>(reinterpret_cast<const char*>(As) + rA * 64 + sw);
        const int rB = wc * 64 + m * 16 + rsel;
        bg[m] = *reinterpret_cast<const v8bf*>(reinterpret_cast<const char*>(Bs) + rB * 64 + sw);
      }
      #pragma unroll
      for (int m = 0; m < 4; ++m)
        #pragma unroll
        for (int n = 0; n < 4; ++n)
          acc[m][n] = __builtin_amdgcn_mfma_f32_16x16x32_bf16(af[m], bg[n], acc[m][n], 0, 0, 0);
    }
  }

  // epilogue: C/D layout col=lane&15, row=(lane>>4)*4+reg
  #pragma unroll
  for (int m = 0; m < 4; ++m) {
    const size_t ri = m0 + wr * 64 + m * 16 + ((lane >> 4) * 4);
    #pragma unroll
    for (int n = 0; n < 4; ++n) {
      const size_t cj = n0 + wc * 64 + n * 16 + (lane & 15);
      float bv = 0.0f;
      if (EPI == 1) bv = bias[cj];
      #pragma unroll
      for (int r = 0; r < 4; ++r) {
        float v = acc[m][n][r];
        if (EPI == 1) v = fmaxf(v + bv, 0.0f);
        Cz[(ri + r) * ldc + cj] = v;
      }
    }
  }
}

// ---------------- softmax over rows, in place, + bf16 copy ----------------
__global__ __launch_bounds__(256) void k_softmax(float* __restrict__ sc,
                                                 bf16* __restrict__ abf) {
  const size_t row = blockIdx.x;
  const int t = threadIdx.x;
  float* s = sc + row * Ls;
  float4 v = reinterpret_cast<float4*>(s)[t];
  float mx = fmaxf(fmaxf(v.x, v.y), fmaxf(v.z, v.w));
  #pragma unroll
  for (int o = 32; o > 0; o >>= 1) mx = fmaxf(mx, __shfl_down(mx, o));
  __shared__ float rm[4], rs[4];
  if ((t & 63) == 0) rm[t >> 6] = mx;
  __syncthreads();
  const float M = fmaxf(fmaxf(rm[0], rm[1]), fmaxf(rm[2], rm[3]));
  float4 e;
  e.x = __expf(v.x - M); e.y = __expf(v.y - M);
  e.z = __expf(v.z - M); e.w = __expf(v.w - M);
  float ss = e.x + e.y + e.z + e.w;
  #pragma unroll
  for (int o = 32; o > 0; o >>= 1) ss += __shfl_down(ss, o);
  if ((t & 63) == 0) rs[t >> 6] = ss;
  __syncthreads();
  const float inv = 1.0f / (rs[0] + rs[1] + rs[2] + rs[3]);
  e.x *= inv; e.y *= inv; e.z *= inv; e.w *= inv;
  reinterpret_cast<float4*>(s)[t] = e;
  bf4 o4 = { __float2bfloat16(e.x), __float2bfloat16(e.y),
             __float2bfloat16(e.z), __float2bfloat16(e.w) };
  reinterpret_cast<bf4*>(abf + row * Ls)[t] = o4;
}

// ---------------- reduce split-K partials -> A2 = [ah | al | ah] ----------------
__global__ __launch_bounds__(256) void k_reduce(const float* __restrict__ part,
                                                bf16* __restrict__ A2) {
  const size_t idx = (size_t)blockIdx.x * 256 + threadIdx.x;   // over L*D/4
  float4 s = {0.f, 0.f, 0.f, 0.f};
  #pragma unroll
  for (int g = 0; g < 16; ++g) {
    const float4 p = reinterpret_cast<const float4*>(part + (size_t)g * (Ls * Ds))[idx];
    s.x += p.x; s.y += p.y; s.z += p.z; s.w += p.w;
  }
  const size_t e0 = idx * 4;
  const size_t i = e0 >> 10, d = e0 & 1023;
  bf4 h, l;
  h.a = __float2bfloat16(s.x); l.a = __float2bfloat16(s.x - __bfloat162float(h.a));
  h.b = __float2bfloat16(s.y); l.b = __float2bfloat16(s.y - __bfloat162float(h.b));
  h.c = __float2bfloat16(s.z); l.c = __float2bfloat16(s.z - __bfloat162float(h.c));
  h.d = __float2bfloat16(s.w); l.d = __float2bfloat16(s.w - __bfloat162float(h.d));
  bf16* row = A2 + i * 3072;
  *reinterpret_cast<bf4*>(row + d) = h;
  *reinterpret_cast<bf4*>(row + 1024 + d) = l;
  *reinterpret_cast<bf4*>(row + 2048 + d) = h;
}

// ---------------- reduce x split-K partials + bias + relu ----------------
__global__ __launch_bounds__(256) void k_reduce2(const float* __restrict__ part2,
                                                 const float* __restrict__ bias,
                                                 float* __restrict__ xout) {
  const size_t idx = (size_t)blockIdx.x * 256 + threadIdx.x;   // over L*H/4
  float4 s = {0.f, 0.f, 0.f, 0.f};
  #pragma unroll
  for (int g = 0; g < 4; ++g) {
    const float4 p = reinterpret_cast<const float4*>(part2 + (size_t)g * (Ls * Hs))[idx];
    s.x += p.x; s.y += p.y; s.z += p.z; s.w += p.w;
  }
  const size_t h0 = (idx * 4) & 1023;
  const float4 bv = *reinterpret_cast<const float4*>(bias + h0);
  s.x = fmaxf(s.x + bv.x, 0.f); s.y = fmaxf(s.y + bv.y, 0.f);
  s.z = fmaxf(s.z + bv.z, 0.f); s.w = fmaxf(s.w + bv.w, 0.f);
  reinterpret_cast<float4*>(xout)[idx] = s;
}

extern "C" void kernel_launch(void* const* d_in, const int* in_sizes, int n_in,
                              void* d_out, int out_size, void* d_ws, size_t ws_size,
                              hipStream_t stream) {
  const float* q = (const float*)d_in[0];
  const float* k = (const float*)d_in[1];
  const float* W = (const float*)d_in[2];
  const float* bias = (const float*)d_in[3];
  float* xout = (float*)d_out;                        // [1024][1024]
  float* attn = (float*)d_out + (size_t)Ls * Hs;      // [32][1024][1024] (scores staged here)

  char* w = (char*)d_ws;
  bf16* qn = (bf16*)w;                                // 64 MB; reused as attn bf16
  bf16* kn = (bf16*)(w + ((size_t)64 << 20));         // 64 MB; reused as partials
  bf16* kT = (bf16*)(w + ((size_t)128 << 20));        // 64 MB; reused as x partials
  bf16* W2 = (bf16*)(w + ((size_t)192 << 20));        // 6 MB
  bf16* A2 = (bf16*)(w + ((size_t)199 << 20));        // 6 MB
  float* part = (float*)kn;                           // 64 MB (16 groups x 4 MB)
  float* part2 = (float*)kT;                          // 16 MB (4 groups x 4 MB)
  bf16* abf = qn;

  k_norm<<<NBATCH * Ls, 256, 0, stream>>>(q, k, qn, kn);
  k_transpose<<<dim3(16, 16, NBATCH), dim3(64, 4), 0, stream>>>(k, kT);
  k_w2<<<(Hs * Ds) / 256, 256, 0, stream>>>(W, W2);

  // scores[b][i][j] = kn_b . qn_b^T  -> fp32 into d_out attn region
  k_gemm_nt<0><<<dim3(8, 8, NBATCH), 256, 0, stream>>>(kn, qn, attn, nullptr,
      Ds, Ds, Ls, Ds, 1, 0, 0,
      (size_t)Ls * Ds, (size_t)Ls * Ds, (size_t)Ls * Ls);

  k_softmax<<<NBATCH * Ls, 256, 0, stream>>>(attn, abf);

  // out partials: 16 z-groups x 2 batches each; C_z[i][d] += attn_b[i,:] . kT_b[d,:]
  k_gemm_nt<0><<<dim3(8, 8, 16), 256, 0, stream>>>(abf, kT, part, nullptr,
      Ls, Ls, Ds, Ls, 2, (size_t)Ls * Ls, (size_t)Ls * Ds,
      (size_t)2 * Ls * Ls, (size_t)2 * Ls * Ds, (size_t)Ls * Ds);

  k_reduce<<<(Ls * Ds / 4) / 256, 256, 0, stream>>>(part, A2);

  // x partials: split-K over 4 z-groups, K=768 each (A2/W2 are K=3072 hi/lo-split)
  k_gemm_nt<0><<<dim3(8, 8, 4), 256, 0, stream>>>(A2, W2, part2, nullptr,
      3072, 3072, Hs, 768, 1, 0, 0, 768, 768, (size_t)Ls * Hs);

  k_reduce2<<<(Ls * Hs / 4) / 256, 256, 0, stream>>>(part2, bias, xout);
}

// Round 4
// 364.560 us; speedup vs baseline: 1.3802x; 1.2561x over previous
//
#include <hip/hip_runtime.h>
#include <hip/hip_bf16.h>

#define NBATCH 32
#define Ls 1024
#define Ds 1024
#define Hs 1024

typedef float f32x4 __attribute__((ext_vector_type(4)));
typedef __bf16 v8bf __attribute__((ext_vector_type(8)));
typedef __hip_bfloat16 bf16;

struct bf4 { bf16 a, b, c, d; };   // 8 bytes

// ---------------- normalize q,k rows -> bf16 (+ raw bf16 keys copy) ----------------
__global__ __launch_bounds__(256) void k_norm(const float* __restrict__ q,
                                              const float* __restrict__ k,
                                              bf16* __restrict__ qn,
                                              bf16* __restrict__ kn,
                                              bf16* __restrict__ kb) {
  const size_t row = blockIdx.x;
  const int t = threadIdx.x;
  const float4 qv = reinterpret_cast<const float4*>(q + row * Ds)[t];
  const float4 kv = reinterpret_cast<const float4*>(k + row * Ds)[t];
  float sq = qv.x*qv.x + qv.y*qv.y + qv.z*qv.z + qv.w*qv.w;
  float sk = kv.x*kv.x + kv.y*kv.y + kv.z*kv.z + kv.w*kv.w;
  #pragma unroll
  for (int o = 32; o > 0; o >>= 1) { sq += __shfl_down(sq, o); sk += __shfl_down(sk, o); }
  __shared__ float rq[4], rk[4];
  if ((t & 63) == 0) { rq[t >> 6] = sq; rk[t >> 6] = sk; }
  __syncthreads();
  const float invq = 1.0f / sqrtf(rq[0] + rq[1] + rq[2] + rq[3]);
  const float invk = 1.0f / sqrtf(rk[0] + rk[1] + rk[2] + rk[3]);
  bf4 oq = { __float2bfloat16(qv.x * invq), __float2bfloat16(qv.y * invq),
             __float2bfloat16(qv.z * invq), __float2bfloat16(qv.w * invq) };
  bf4 ok = { __float2bfloat16(kv.x * invk), __float2bfloat16(kv.y * invk),
             __float2bfloat16(kv.z * invk), __float2bfloat16(kv.w * invk) };
  bf4 ob = { __float2bfloat16(kv.x), __float2bfloat16(kv.y),
             __float2bfloat16(kv.z), __float2bfloat16(kv.w) };
  reinterpret_cast<bf4*>(qn + row * Ds)[t] = oq;
  reinterpret_cast<bf4*>(kn + row * Ds)[t] = ok;
  reinterpret_cast<bf4*>(kb + row * Ds)[t] = ob;
}

// ---------------- keys(bf16) -> keysT bf16 (per batch) ----------------
__global__ __launch_bounds__(256) void k_transpose(const bf16* __restrict__ kb,
                                                   bf16* __restrict__ kT) {
  __shared__ float tile[64][65];
  const int b = blockIdx.z;
  const int d0 = blockIdx.x * 64, j0 = blockIdx.y * 64;
  const int tx = threadIdx.x, ty = threadIdx.y;
  const bf16* src = kb + (size_t)b * Ls * Ds;
  #pragma unroll
  for (int r = 0; r < 16; ++r)
    tile[ty + r * 4][tx] = __bfloat162float(src[(size_t)(j0 + ty + r * 4) * Ds + d0 + tx]);
  __syncthreads();
  bf16* dst = kT + (size_t)b * Ds * Ls;
  #pragma unroll
  for (int r = 0; r < 16; ++r)
    dst[(size_t)(d0 + ty + r * 4) * Ls + j0 + tx] = __float2bfloat16(tile[tx][ty + r * 4]);
}

// ---------------- W -> W2 = [wh | wh | wl] bf16 ----------------
__global__ __launch_bounds__(256) void k_w2(const float* __restrict__ W,
                                            bf16* __restrict__ W2) {
  const size_t idx = (size_t)blockIdx.x * 256 + threadIdx.x;   // over H*D
  const size_t h = idx >> 10, d = idx & 1023;
  const float w = W[idx];
  const bf16 wh = __float2bfloat16(w);
  const bf16 wl = __float2bfloat16(w - __bfloat162float(wh));
  bf16* row = W2 + h * 3072;
  row[d] = wh; row[1024 + d] = wh; row[2048 + d] = wl;
}

// ============ 256x256 tile, BK=64, 8 waves, counted-vmcnt pipelined NT GEMM ============
// C[i][j] = sum_b sum_k A[i,k]*B[j,k].  LDS 128 KiB (2 buffers x (A,B) x 256x64 bf16).
// Swizzle: slot (row,s) holds global k-slice s^(row&7); store side permutes the GLOBAL
// source address (LDS dest linear, rule 21), read side XORs the ds_read address.
// Pipeline: stage tile t+1 while computing tile t; boundary wait = vmcnt(8) (the 8
// just-issued loads), never vmcnt(0) in the loop. Raw s_barrier (no implicit drain).
template<int KT>   // 64-wide K-tiles per batch
__global__ __launch_bounds__(512) void k_gemm256(
    const bf16* __restrict__ A, const bf16* __restrict__ B,
    float* __restrict__ C,
    int lda, int ldb, int ldc, int nb,
    size_t sA, size_t sB, size_t zA, size_t zB, size_t zC)
{
  __shared__ bf16 lds[2][2][256 * 64];
  const int tid = threadIdx.x;
  const int lane = tid & 63;
  const int wid = tid >> 6;
  const int wr = wid >> 2;            // 0..1  (M)
  const int wc = wid & 3;             // 0..3  (N)
  const size_t m0 = (size_t)blockIdx.y * 256;
  const size_t n0 = (size_t)blockIdx.x * 256;
  const bf16* Az = A + (size_t)blockIdx.z * zA;
  const bf16* Bz = B + (size_t)blockIdx.z * zB;
  float* Cz = C + (size_t)blockIdx.z * zC;

  const int srow = tid >> 3;          // 0..63 row-within-chunk
  const int sslot = tid & 7;          // 16B slot
  f32x4 acc[8][4] = {};

  auto stage = [&](int tt, int buf) {
    const int b = tt / KT;
    const int k0 = (tt - b * KT) * 64;
    const bf16* Ab = Az + (size_t)b * sA;
    const bf16* Bb = Bz + (size_t)b * sB;
    #pragma unroll
    for (int c = 0; c < 4; ++c) {
      const int row = c * 64 + srow;
      const int ksl = (sslot ^ (row & 7)) * 8;
      __builtin_amdgcn_global_load_lds(
          (const __attribute__((address_space(1))) void*)(Ab + (m0 + row) * lda + k0 + ksl),
          (__attribute__((address_space(3))) void*)(&lds[buf][0][c * 4096 + tid * 8]), 16, 0, 0);
    }
    #pragma unroll
    for (int c = 0; c < 4; ++c) {
      const int row = c * 64 + srow;
      const int ksl = (sslot ^ (row & 7)) * 8;
      __builtin_amdgcn_global_load_lds(
          (const __attribute__((address_space(1))) void*)(Bb + (n0 + row) * ldb + k0 + ksl),
          (__attribute__((address_space(3))) void*)(&lds[buf][1][c * 4096 + tid * 8]), 16, 0, 0);
    }
  };

  const int rsel = lane & 15, qd = lane >> 4;
  auto compute = [&](int buf) {
    const bf16* As = lds[buf][0];
    const bf16* Bs = lds[buf][1];
    v8bf bfrag[2][4];
    #pragma unroll
    for (int h = 0; h < 2; ++h)
      #pragma unroll
      for (int n = 0; n < 4; ++n) {
        const int r = wc * 64 + n * 16 + rsel;
        const int s = (h * 4 + qd) ^ (r & 7);
        bfrag[h][n] = *reinterpret_cast<const v8bf*>(
            reinterpret_cast<const char*>(Bs) + r * 128 + s * 16);
      }
    #pragma unroll
    for (int m = 0; m < 8; ++m) {
      const int r = wr * 128 + m * 16 + rsel;
      const int s0 = qd ^ (r & 7);
      const int s1 = (4 + qd) ^ (r & 7);
      const v8bf a0 = *reinterpret_cast<const v8bf*>(
          reinterpret_cast<const char*>(As) + r * 128 + s0 * 16);
      const v8bf a1 = *reinterpret_cast<const v8bf*>(
          reinterpret_cast<const char*>(As) + r * 128 + s1 * 16);
      #pragma unroll
      for (int n = 0; n < 4; ++n)
        acc[m][n] = __builtin_amdgcn_mfma_f32_16x16x32_bf16(a0, bfrag[0][n], acc[m][n], 0, 0, 0);
      #pragma unroll
      for (int n = 0; n < 4; ++n)
        acc[m][n] = __builtin_amdgcn_mfma_f32_16x16x32_bf16(a1, bfrag[1][n], acc[m][n], 0, 0, 0);
    }
  };

  const int T = KT * nb;
  stage(0, 0);
  for (int t = 0; t < T - 1; ++t) {
    __builtin_amdgcn_s_barrier();                       // everyone done reading buf[(t+1)&1]
    stage(t + 1, (t + 1) & 1);
    asm volatile("s_waitcnt vmcnt(8)" ::: "memory");    // tile t fully resident (in-order retire)
    __builtin_amdgcn_s_barrier();                       // all waves' tile-t loads visible
    compute(t & 1);
  }
  asm volatile("s_waitcnt vmcnt(0)" ::: "memory");
  __builtin_amdgcn_s_barrier();
  compute((T - 1) & 1);

  // epilogue: C/D layout col=lane&15, row=(lane>>4)*4+reg
  #pragma unroll
  for (int m = 0; m < 8; ++m) {
    const size_t ri = m0 + wr * 128 + m * 16 + (size_t)((lane >> 4) * 4);
    #pragma unroll
    for (int n = 0; n < 4; ++n) {
      const size_t cj = n0 + wc * 64 + n * 16 + (lane & 15);
      #pragma unroll
      for (int r = 0; r < 4; ++r)
        Cz[(ri + r) * ldc + cj] = acc[m][n][r];
    }
  }
}

// ---------------- 128x128 NT GEMM (kept for the small x-GEMM) ----------------
__global__ __launch_bounds__(256) void k_gemm_nt(
    const bf16* __restrict__ A, const bf16* __restrict__ B,
    float* __restrict__ C,
    int lda, int ldb, int ldc, int K,
    size_t zA, size_t zB, size_t zC)
{
  __shared__ bf16 As[128 * 32];
  __shared__ bf16 Bs[128 * 32];
  const int tid = threadIdx.x;
  const int lane = tid & 63;
  const int wc = (tid >> 6) & 1;
  const int wr = (tid >> 7) & 1;
  const size_t m0 = (size_t)blockIdx.y * 128;
  const size_t n0 = (size_t)blockIdx.x * 128;
  const bf16* Az = A + (size_t)blockIdx.z * zA;
  const bf16* Bz = B + (size_t)blockIdx.z * zB;
  float* Cz = C + (size_t)blockIdx.z * zC;
  f32x4 acc[4][4] = {};

  const int beta0 = tid * 16;
  const int row0 = tid >> 2;
  const int kk0 = ((tid & 3) ^ ((row0 >> 1) & 3)) * 8;
  const int sw = (((lane >> 4) ^ ((lane >> 1) & 3)) << 4);
  const int rsel = lane & 15;

  for (int k0 = 0; k0 < K; k0 += 32) {
    __syncthreads();
    __builtin_amdgcn_global_load_lds(
        (const __attribute__((address_space(1))) void*)(Az + (m0 + row0) * lda + (k0 + kk0)),
        (__attribute__((address_space(3))) void*)(&As[beta0 / 2]), 16, 0, 0);
    __builtin_amdgcn_global_load_lds(
        (const __attribute__((address_space(1))) void*)(Az + (m0 + row0 + 64) * lda + (k0 + kk0)),
        (__attribute__((address_space(3))) void*)(&As[beta0 / 2 + 2048]), 16, 0, 0);
    __builtin_amdgcn_global_load_lds(
        (const __attribute__((address_space(1))) void*)(Bz + (n0 + row0) * ldb + (k0 + kk0)),
        (__attribute__((address_space(3))) void*)(&Bs[beta0 / 2]), 16, 0, 0);
    __builtin_amdgcn_global_load_lds(
        (const __attribute__((address_space(1))) void*)(Bz + (n0 + row0 + 64) * ldb + (k0 + kk0)),
        (__attribute__((address_space(3))) void*)(&Bs[beta0 / 2 + 2048]), 16, 0, 0);
    __syncthreads();

    v8bf af[4], bg[4];
    #pragma unroll
    for (int m = 0; m < 4; ++m) {
      const int rA = wr * 64 + m * 16 + rsel;
      af[m] = *reinterpret_cast<const v8bf*>(reinterpret_cast<const char*>(As) + rA * 64 + sw);
      const int rB = wc * 64 + m * 16 + rsel;
      bg[m] = *reinterpret_cast<const v8bf*>(reinterpret_cast<const char*>(Bs) + rB * 64 + sw);
    }
    #pragma unroll
    for (int m = 0; m < 4; ++m)
      #pragma unroll
      for (int n = 0; n < 4; ++n)
        acc[m][n] = __builtin_amdgcn_mfma_f32_16x16x32_bf16(af[m], bg[n], acc[m][n], 0, 0, 0);
  }

  #pragma unroll
  for (int m = 0; m < 4; ++m) {
    const size_t ri = m0 + wr * 64 + m * 16 + ((lane >> 4) * 4);
    #pragma unroll
    for (int n = 0; n < 4; ++n) {
      const size_t cj = n0 + wc * 64 + n * 16 + (lane & 15);
      #pragma unroll
      for (int r = 0; r < 4; ++r)
        Cz[(ri + r) * ldc + cj] = acc[m][n][r];
    }
  }
}

// ---------------- softmax over rows, in place, + bf16 copy ----------------
__global__ __launch_bounds__(256) void k_softmax(float* __restrict__ sc,
                                                 bf16* __restrict__ abf) {
  const size_t row = blockIdx.x;
  const int t = threadIdx.x;
  float* s = sc + row * Ls;
  float4 v = reinterpret_cast<float4*>(s)[t];
  float mx = fmaxf(fmaxf(v.x, v.y), fmaxf(v.z, v.w));
  #pragma unroll
  for (int o = 32; o > 0; o >>= 1) mx = fmaxf(mx, __shfl_down(mx, o));
  __shared__ float rm[4], rs[4];
  if ((t & 63) == 0) rm[t >> 6] = mx;
  __syncthreads();
  const float M = fmaxf(fmaxf(rm[0], rm[1]), fmaxf(rm[2], rm[3]));
  float4 e;
  e.x = __expf(v.x - M); e.y = __expf(v.y - M);
  e.z = __expf(v.z - M); e.w = __expf(v.w - M);
  float ss = e.x + e.y + e.z + e.w;
  #pragma unroll
  for (int o = 32; o > 0; o >>= 1) ss += __shfl_down(ss, o);
  if ((t & 63) == 0) rs[t >> 6] = ss;
  __syncthreads();
  const float inv = 1.0f / (rs[0] + rs[1] + rs[2] + rs[3]);
  e.x *= inv; e.y *= inv; e.z *= inv; e.w *= inv;
  reinterpret_cast<float4*>(s)[t] = e;
  bf4 o4 = { __float2bfloat16(e.x), __float2bfloat16(e.y),
             __float2bfloat16(e.z), __float2bfloat16(e.w) };
  reinterpret_cast<bf4*>(abf + row * Ls)[t] = o4;
}

// ---------------- reduce split-K partials -> A2 = [ah | al | ah] ----------------
__global__ __launch_bounds__(256) void k_reduce(const float* __restrict__ part,
                                                bf16* __restrict__ A2) {
  const size_t idx = (size_t)blockIdx.x * 256 + threadIdx.x;   // over L*D/4
  float4 s = {0.f, 0.f, 0.f, 0.f};
  #pragma unroll
  for (int g = 0; g < 16; ++g) {
    const float4 p = reinterpret_cast<const float4*>(part + (size_t)g * (Ls * Ds))[idx];
    s.x += p.x; s.y += p.y; s.z += p.z; s.w += p.w;
  }
  const size_t e0 = idx * 4;
  const size_t i = e0 >> 10, d = e0 & 1023;
  bf4 h, l;
  h.a = __float2bfloat16(s.x); l.a = __float2bfloat16(s.x - __bfloat162float(h.a));
  h.b = __float2bfloat16(s.y); l.b = __float2bfloat16(s.y - __bfloat162float(h.b));
  h.c = __float2bfloat16(s.z); l.c = __float2bfloat16(s.z - __bfloat162float(h.c));
  h.d = __float2bfloat16(s.w); l.d = __float2bfloat16(s.w - __bfloat162float(h.d));
  bf16* row = A2 + i * 3072;
  *reinterpret_cast<bf4*>(row + d) = h;
  *reinterpret_cast<bf4*>(row + 1024 + d) = l;
  *reinterpret_cast<bf4*>(row + 2048 + d) = h;
}

// ---------------- reduce x split-K partials + bias + relu ----------------
__global__ __launch_bounds__(256) void k_reduce2(const float* __restrict__ part2,
                                                 const float* __restrict__ bias,
                                                 float* __restrict__ xout) {
  const size_t idx = (size_t)blockIdx.x * 256 + threadIdx.x;   // over L*H/4
  float4 s = {0.f, 0.f, 0.f, 0.f};
  #pragma unroll
  for (int g = 0; g < 4; ++g) {
    const float4 p = reinterpret_cast<const float4*>(part2 + (size_t)g * (Ls * Hs))[idx];
    s.x += p.x; s.y += p.y; s.z += p.z; s.w += p.w;
  }
  const size_t h0 = (idx * 4) & 1023;
  const float4 bv = *reinterpret_cast<const float4*>(bias + h0);
  s.x = fmaxf(s.x + bv.x, 0.f); s.y = fmaxf(s.y + bv.y, 0.f);
  s.z = fmaxf(s.z + bv.z, 0.f); s.w = fmaxf(s.w + bv.w, 0.f);
  reinterpret_cast<float4*>(xout)[idx] = s;
}

extern "C" void kernel_launch(void* const* d_in, const int* in_sizes, int n_in,
                              void* d_out, int out_size, void* d_ws, size_t ws_size,
                              hipStream_t stream) {
  const float* q = (const float*)d_in[0];
  const float* k = (const float*)d_in[1];
  const float* W = (const float*)d_in[2];
  const float* bias = (const float*)d_in[3];
  float* xout = (float*)d_out;                        // [1024][1024]
  float* attn = (float*)d_out + (size_t)Ls * Hs;      // [32][1024][1024] (scores staged here)

  char* w = (char*)d_ws;
  bf16* qn = (bf16*)w;                                // 64 MB; reused as attn bf16
  bf16* kn = (bf16*)(w + ((size_t)64 << 20));         // 64 MB; reused as partials
  bf16* kT = (bf16*)(w + ((size_t)128 << 20));        // 64 MB; reused as x partials
  bf16* kb = (bf16*)(w + ((size_t)208 << 20));        // 64 MB raw bf16 keys
  bf16* W2 = (bf16*)(w + ((size_t)192 << 20));        // 6 MB
  bf16* A2 = (bf16*)(w + ((size_t)199 << 20));        // 6 MB
  float* part = (float*)kn;                           // 64 MB (16 groups x 4 MB)
  float* part2 = (float*)kT;                          // 16 MB (4 groups x 4 MB)
  bf16* abf = qn;

  k_norm<<<NBATCH * Ls, 256, 0, stream>>>(q, k, qn, kn, kb);
  k_transpose<<<dim3(16, 16, NBATCH), dim3(64, 4), 0, stream>>>(kb, kT);
  k_w2<<<(Hs * Ds) / 256, 256, 0, stream>>>(W, W2);

  // scores[b][i][j] = kn_b . qn_b^T  -> fp32 into d_out attn region
  k_gemm256<16><<<dim3(4, 4, NBATCH), 512, 0, stream>>>(kn, qn, attn,
      Ds, Ds, Ls, 1,
      (size_t)Ls * Ds, (size_t)Ls * Ds,
      (size_t)Ls * Ds, (size_t)Ls * Ds, (size_t)Ls * Ls);

  k_softmax<<<NBATCH * Ls, 256, 0, stream>>>(attn, abf);

  // out partials: 16 z-groups x 2 batches each; C_z[i][d] += attn_b[i,:] . kT_b[d,:]
  k_gemm256<16><<<dim3(4, 4, 16), 512, 0, stream>>>(abf, kT, part,
      Ls, Ls, Ds, 2,
      (size_t)Ls * Ls, (size_t)Ls * Ds,
      (size_t)2 * Ls * Ls, (size_t)2 * Ls * Ds, (size_t)Ls * Ds);

  k_reduce<<<(Ls * Ds / 4) / 256, 256, 0, stream>>>(part, A2);

  // x partials: split-K over 4 z-groups, K=768 each (A2/W2 are K=3072 hi/lo-split)
  k_gemm_nt<<<dim3(8, 8, 4), 256, 0, stream>>>(A2, W2, part2,
      3072, 3072, Hs, 768, 768, 768, (size_t)Ls * Hs);

  k_reduce2<<<(Ls * Hs / 4) / 256, 256, 0, stream>>>(part2, bias, xout);
}